// Round 6
// baseline (267.407 us; speedup 1.0000x reference)
//
#include <hip/hip_runtime.h>
#include <math.h>

// EquivariantWSSHead: V=100000 vertices, E=1600000 edges, C0=C1=16.
//
// R1..R15: bucket binning; bf16 table; fixed-point INT LDS accumulate.
// R16/R18: in-kernel deletions NEUTRAL => cost is structural.
// R19 PROBE: kernel trio = 43.6us, harness floor = 94.7us.
// R20 PROBE (failed design, good data): global u64 atomics = 147us for
//   3.2M ops (46ns each, 100MB WRITE_SIZE at coherence point) => global-
//   atomic design dead. Also: P + F + 2 gaps = 6us => precompute ~5us,
//   finalize ~1us. Therefore scatter+bucket = ~38us vs ~8us traffic.
// R21 (this round): PURE PROBE to split S vs B. Scatter runs 8x: 7
//   replays against a scratch cursor fill2 (real fill untouched, so the
//   final scatter+bucket produce bit-identical output to R18), then the
//   real scatter + bucket.  S+gap = (dur - 138.3)/7;  B = 38 - S.
//   Pre-committed read: S+gap in [20,30] => scatter is the whale, next
//   round restructures scatter. S ~ 10 => bucket is the whale.
//   Replay safety: fill2 zeroed by P; replay writes stay clamped inside
//   each bin's payload region; final scatter rewrites every slot bucket
//   reads; int accumulate is order-invariant.

#define VB 256           // vertices per bucket
#define VB_SHIFT 8
#define MAXNB 400        // NB = ceil(V/256) = 391 for V=100000
#define CHUNK 3125       // edges per chunk
#define NCHUNK 512       // chunks (E/CHUNK)
#define BIGT 1024
#define CAP_SHIFT 13
#define CAP (1 << CAP_SHIFT)   // 8192 payload slots per bin
#define FIXS 131072.0f   // 2^17 fixed-point scale
#define FIXSI (1.0f / 131072.0f)
#define BIASI (1 << 22)  // low-field bias (|v_fix| < 2^22 since |v| < 32)

typedef unsigned int uint32;
typedef unsigned long long uint64;

static __device__ __forceinline__ uint32 f2bf(float f) {
    uint32 u = __float_as_uint(f);
    return (u + 0x7FFFu + ((u >> 16) & 1u)) >> 16;   // RNE to bf16
}
static __device__ __forceinline__ uint32 pack2(float lo, float hi) {
    return f2bf(lo) | (f2bf(hi) << 16);
}
static __device__ __forceinline__ float bf_lo(uint32 u) {
    return __uint_as_float(u << 16);
}
static __device__ __forceinline__ float bf_hi(uint32 u) {
    return __uint_as_float(u & 0xFFFF0000u);
}

// K1: per-vertex dot-product table (256 rows staged in LDS, stride 49
// floats, conflict-free). Block 0 zeroes BOTH cursors (fill + fill2).
__global__ __launch_bounds__(256)
void precompute_kernel(const float* __restrict__ x,
                       const float* __restrict__ w_self0,
                       const float* __restrict__ w_n00,
                       const float* __restrict__ w_n10,
                       const float* __restrict__ w_self11,
                       const float* __restrict__ w_n01,
                       const float* __restrict__ w_n11,
                       uint32* __restrict__ table,   // 8 u32/vertex
                       float* __restrict__ selfbuf,
                       int* __restrict__ fill,       // 2*MAXNB cursors
                       int V, int NB) {
    __shared__ float stage[256 * 49];   // 50KB
    int tid = threadIdx.x;
    if (blockIdx.x == 0) {
        for (int i = tid; i < 2 * MAXNB; i += 256) fill[i] = 0;
    }
    int v0 = blockIdx.x * 256;
    int nv = min(256, V - v0);
    if (nv <= 0) return;
    {
        const float4* x4 = (const float4*)(x + (size_t)v0 * 48);
        int n4 = nv * 12;
        for (int j = tid; j < n4; j += 256) {
            float4 f = x4[j];
            float* dp = stage + (j / 12) * 49 + (j % 12) * 4;
            dp[0] = f.x; dp[1] = f.y; dp[2] = f.z; dp[3] = f.w;
        }
    }
    __syncthreads();
    if (tid >= nv) return;
    int v = v0 + tid;
    const float* xr = stage + tid * 49;
    float d00 = 0.f, aw0 = 0.f, bw0 = 0.f, aw1 = 0.f, bw1 = 0.f;
    float d01a = 0.f, d01b = 0.f;
    float aP = 0.f, bP = 0.f, aQ = 0.f, bQ = 0.f;
    float aR = 0.f, bR = 0.f, aS = 0.f, bS = 0.f;
    float selfmag = 0.f, t1s = 0.f, t2s = 0.f;
#pragma unroll
    for (int i = 0; i < 16; ++i) {
        float x0 = xr[i];
        float a  = xr[16 + 2 * i];
        float b  = xr[17 + 2 * i];
        d00     += x0 * w_n00[i];
        selfmag += x0 * w_self0[i];
        d01a    += x0 * w_n01[i * 2 + 0];
        d01b    += x0 * w_n01[i * 2 + 1];
        float w0 = w_n10[i * 2 + 0], w1 = w_n10[i * 2 + 1];
        aw0 += a * w0;  bw0 += b * w0;
        aw1 += a * w1;  bw1 += b * w1;
        float p = w_n11[i * 4 + 0], q = w_n11[i * 4 + 1];
        float r = w_n11[i * 4 + 2], s = w_n11[i * 4 + 3];
        aP += a * p;  bP += b * p;
        aQ += a * q;  bQ += b * q;
        aR += a * r;  bR += b * r;
        aS += a * s;  bS += b * s;
        float sa_ = w_self11[i * 2 + 0], sb_ = w_self11[i * 2 + 1];
        t1s += a * sa_ - b * sb_;
        t2s += b * sa_ + a * sb_;
    }
    uint4 w0, w1;
    w0.x = pack2(d00, aw0);  w0.y = pack2(bw0, aw1);
    w0.z = pack2(bw1, d01a); w0.w = pack2(d01b, aP);
    w1.x = pack2(bP, aQ);    w1.y = pack2(bQ, aR);
    w1.z = pack2(bR, aS);    w1.w = pack2(bS, 0.f);
    uint4* tp = (uint4*)(table + (size_t)v * 8);
    tp[0] = w0;  tp[1] = w1;
    float* sf = selfbuf + (size_t)v * 4;
    sf[0] = selfmag; sf[1] = t1s; sf[2] = t2s; sf[3] = 0.f;
}

// K2: per-chunk LDS tuple-sort + compute + write into the bin's global
// region reserved via one atomicAdd per (chunk,bin).
__global__ __launch_bounds__(BIGT)
void scatter_kernel(const int* __restrict__ src,
                    const int* __restrict__ dst,
                    const float* __restrict__ angles,
                    const float* __restrict__ transporters,
                    const uint32* __restrict__ table,
                    int* __restrict__ fill,
                    uint2* __restrict__ payload,
                    int E, int NB) {
    __shared__ int cnt_l[MAXNB];
    __shared__ int exoff_l[MAXNB];
    __shared__ int slot_l[MAXNB];
    __shared__ int wsum[16];
    __shared__ uint32 tw_src[CHUNK];
    __shared__ uint32 tw_ang[CHUNK];
    __shared__ uint32 tw_tr[CHUNK];
    __shared__ unsigned short tw_bin[CHUNK];

    int b = blockIdx.x;
    int lo = b * CHUNK;
    int hi = min(E, lo + CHUNK);
    int nloc = hi - lo;
    int tid = threadIdx.x;
    int lane = tid & 63;
    int wv = tid >> 6;

    for (int i = tid; i < NB; i += BIGT) cnt_l[i] = 0;
    __syncthreads();

    // pass1: chunk histogram (dst stays L1-warm for pass1b)
    for (int e = lo + tid; e < hi; e += BIGT)
        atomicAdd(&cnt_l[dst[e] >> VB_SHIFT], 1);
    __syncthreads();

    // reserve global bin space NOW (latency overlaps the scan below)
    int c = (tid < NB) ? cnt_l[tid] : 0;
    int rsv = 0;
    if (tid < NB && c > 0) rsv = atomicAdd(&fill[tid], c);

    // exclusive scan of chunk bin counts -> local sort offsets
    int incl = c;
#pragma unroll
    for (int d = 1; d < 64; d <<= 1) {
        int n = __shfl_up(incl, d);
        if (lane >= d) incl += n;
    }
    if (lane == 63) wsum[wv] = incl;
    __syncthreads();
    if (tid < 16) {
        int wval = wsum[tid], winc = wval;
#pragma unroll
        for (int d = 1; d < 16; d <<= 1) {
            int n = __shfl_up(winc, d);
            if (lane >= d) winc += n;
        }
        wsum[tid] = winc - wval;
    }
    __syncthreads();
    if (tid < NB) {
        int ex = incl - c + wsum[wv];
        exoff_l[tid] = ex;
        cnt_l[tid] = ex;                             // cursor
        slot_l[tid] = (tid << CAP_SHIFT) + rsv;      // global run start
    }
    __syncthreads();

    // pass1b: coalesced reads; tuple -> bin-sorted LDS slot
    for (int e = lo + tid; e < hi; e += BIGT) {
        int d = dst[e];
        int bin = d >> VB_SHIFT;
        uint32 dl = (uint32)(d & (VB - 1));
        int pos = atomicAdd(&cnt_l[bin], 1);
        tw_src[pos] = (uint32)src[e] | (dl << 17);
        tw_ang[pos] = __float_as_uint(angles[e]);
        tw_tr[pos]  = __float_as_uint(transporters[e]);
        tw_bin[pos] = (unsigned short)bin;
    }
    __syncthreads();

    // pass2: compute in bin order, write contiguous bin-region runs
    for (int k = tid; k < nloc; k += BIGT) {
        int bin = (int)tw_bin[k];
        uint32 w0i = tw_src[k];
        int s  = (int)(w0i & 0x1FFFFu);
        int dl = (int)(w0i >> 17);
        float ang = __uint_as_float(tw_ang[k]);
        float trv = __uint_as_float(tw_tr[k]);
        // native trig: args in [0, 2pi), err ~1e-6 << bf16 payload err
        float st = __sinf(ang), ct = __cosf(ang);
        float sg = __sinf(trv), cg = __cosf(trv);
        float c2t = ct * ct - st * st;
        float s2t = 2.0f * st * ct;

        const uint4* tp = (const uint4*)(table + (size_t)s * 8);
        uint4 W0 = tp[0], W1 = tp[1];
        float d00 = bf_lo(W0.x), aw0 = bf_hi(W0.x);
        float bw0 = bf_lo(W0.y), aw1 = bf_hi(W0.y);
        float bw1 = bf_lo(W0.z), d01a = bf_hi(W0.z);
        float d01b = bf_lo(W0.w), aP = bf_hi(W0.w);
        float bP = bf_lo(W1.x), aQ = bf_hi(W1.x);
        float bQ = bf_lo(W1.y), aR = bf_hi(W1.y);
        float bR = bf_lo(W1.z), aS = bf_hi(W1.z);
        float bS = bf_lo(W1.w);

        float u1w0 = cg * aw0 - sg * bw0, u2w0 = sg * aw0 + cg * bw0;
        float u1w1 = cg * aw1 - sg * bw1, u2w1 = sg * aw1 + cg * bw1;
        float m0 = d00 + ct * u1w0 + st * u2w0 - st * u1w1 + ct * u2w1;

        float u1p = cg * aP - sg * bP, u2p = sg * aP + cg * bP;
        float u1q = cg * aQ - sg * bQ, u2q = sg * aQ + cg * bQ;
        float u1r = cg * aR - sg * bR, u2r = sg * aR + cg * bR;
        float u1s = cg * aS - sg * bS, u2s = sg * aS + cg * bS;

        float mv1 = d01a * ct - d01b * st
                  + u1p - u2q
                  + c2t * u1r + s2t * u2r
                  - (s2t * u1s - c2t * u2s);
        float mv2 = d01a * st + d01b * ct
                  + u2p + u1q
                  + s2t * u1r - c2t * u2r
                  + c2t * u1s + s2t * u2s;

        uint2 pl;
        pl.x = pack2(m0, mv1);
        pl.y = f2bf(mv2) | ((uint32)dl << 16);
        int g = slot_l[bin] + (k - exoff_l[bin]);
        if (g < ((bin + 1) << CAP_SHIFT))            // overflow clamp
            payload[g] = pl;
    }
}

// K3: one block per bin. Dense contiguous read of payload[bin<<13 ..
// +fill[bin]); TWO packed u64 fixed-point LDS atomics per edge; fused
// finalize.
__global__ __launch_bounds__(BIGT)
void bucket_kernel(const uint2* __restrict__ payload,
                   const int* __restrict__ fill,
                   const float* __restrict__ selfbuf,
                   const float* __restrict__ e1,
                   const float* __restrict__ e2,
                   float* __restrict__ out,
                   int V) {
    __shared__ uint64 acc[8][VB * 2];    // 32KB, wave-pair w=tid>>7 owns copy
    int bin = blockIdx.x;
    int tid = threadIdx.x;
    for (int i = tid; i < 8 * VB * 2; i += BIGT) ((uint64*)acc)[i] = 0ULL;
    __syncthreads();

    int n = min(fill[bin], CAP);
    const uint2* pp = payload + ((size_t)bin << CAP_SHIFT);
    uint64* myacc = acc[tid >> 7];
    for (int k = tid; k < n; k += BIGT) {
        uint2 pl = pp[k];
        float m0  = bf_lo(pl.x);
        float mv1 = bf_hi(pl.x);
        float mv2 = bf_lo(pl.y);
        int dl = (int)(pl.y >> 16);
        int m0f  = __float2int_rn(m0  * FIXS);
        int mv1f = __float2int_rn(mv1 * FIXS);
        int mv2f = __float2int_rn(mv2 * FIXS);
        uint64 pa = (uint64)(uint32)(m0f + BIASI)
                  | ((uint64)(uint32)mv1f << 32);
        uint64 pb = (uint64)(uint32)(mv2f + BIASI)
                  | (1ULL << 32);
        atomicAdd(&myacc[dl * 2 + 0], pa);
        atomicAdd(&myacc[dl * 2 + 1], pb);
    }
    __syncthreads();
    if (tid < VB) {
        int v = bin * VB + tid;
        if (v < V) {
            int cnt = 0, m0s = 0, mv1s = 0, mv2s = 0;
#pragma unroll
            for (int w = 0; w < 8; ++w) {
                uint64 a = acc[w][tid * 2 + 0];
                uint64 b = acc[w][tid * 2 + 1];
                uint32 nw = (uint32)(b >> 32);
                cnt  += (int)nw;
                m0s  += (int)((uint32)a - nw * (uint32)BIASI);
                mv1s += (int)(a >> 32);
                mv2s += (int)((uint32)b - nw * (uint32)BIASI);
            }
            float A0 = (float)m0s  * FIXSI;
            float A1 = (float)mv1s * FIXSI;
            float A2 = (float)mv2s * FIXSI;
            float inv = 1.0f / fmaxf((float)cnt, 1.0f);
            const float* sf = selfbuf + (size_t)v * 4;
            float mag = A0 * inv + sf[0];
            float t1  = A1 * inv + sf[1];
            float t2  = A2 * inv + sf[2];
            float scale = 2.0f / (1.0f + expf(-mag));
            float e1x = e1[v * 3 + 0], e1y = e1[v * 3 + 1], e1z = e1[v * 3 + 2];
            float e2x = e2[v * 3 + 0], e2y = e2[v * 3 + 1], e2z = e2[v * 3 + 2];
            out[v * 3 + 0] = (t1 * e1x + t2 * e2x) * scale;
            out[v * 3 + 1] = (t1 * e1y + t2 * e2y) * scale;
            out[v * 3 + 2] = (t1 * e1z + t2 * e2z) * scale;
        }
    }
}

extern "C" void kernel_launch(void* const* d_in, const int* in_sizes, int n_in,
                              void* d_out, int out_size, void* d_ws, size_t ws_size,
                              hipStream_t stream) {
    const float* x            = (const float*)d_in[0];
    const int*   edge_index   = (const int*)d_in[1];
    const float* angles       = (const float*)d_in[2];
    const float* transporters = (const float*)d_in[3];
    const float* e1           = (const float*)d_in[4];
    const float* e2           = (const float*)d_in[5];
    const float* w_self0      = (const float*)d_in[6];
    const float* w_n00        = (const float*)d_in[7];
    const float* w_n10        = (const float*)d_in[8];
    const float* w_self11     = (const float*)d_in[9];
    const float* w_n01        = (const float*)d_in[10];
    const float* w_n11        = (const float*)d_in[11];
    float* out = (float*)d_out;

    int V = in_sizes[0] / 48;
    int E = in_sizes[2];
    const int* src = edge_index;
    const int* dst = edge_index + E;

    int NB = (V + VB - 1) / VB;              // 391
    int nchunk = (E + CHUNK - 1) / CHUNK;    // 512

    char* p = (char*)d_ws;
    int* fill      = (int*)p;     p += (size_t)2 * MAXNB * 4;  // fill + fill2
    uint32* table  = (uint32*)p;  p += (size_t)V * 8 * 4;         // 3.2MB
    float* selfbuf = (float*)p;   p += (size_t)V * 4 * 4;         // 1.6MB
    p = (char*)(((uintptr_t)p + 63) & ~(uintptr_t)63);
    uint2* payload = (uint2*)p;   // MAXNB * CAP * 8B = 26.2MB

    int gv = (V + 255) / 256;                // 391
    int* fill2 = fill + MAXNB;               // scratch cursor for replays

    precompute_kernel<<<gv, 256, 0, stream>>>(
        x, w_self0, w_n00, w_n10, w_self11, w_n01, w_n11,
        table, selfbuf, fill, V, NB);
    // R21 PROBE: 7 scatter replays on the scratch cursor (output-neutral;
    // clamp keeps writes in-region; final scatter rewrites all read slots)
    for (int r = 0; r < 7; ++r)
        scatter_kernel<<<nchunk, BIGT, 0, stream>>>(src, dst, angles,
                                                    transporters, table,
                                                    fill2, payload, E, NB);
    scatter_kernel<<<nchunk, BIGT, 0, stream>>>(src, dst, angles,
                                                transporters, table,
                                                fill, payload, E, NB);
    bucket_kernel<<<NB, BIGT, 0, stream>>>(payload, fill, selfbuf,
                                           e1, e2, out, V);
}

// Round 7
// 164.782 us; speedup vs baseline: 1.6228x; 1.6228x over previous
//
#include <hip/hip_runtime.h>
#include <math.h>

// EquivariantWSSHead: V=100000 vertices, E=1600000 edges, C0=C1=16.
//
// R1..R15: bucket binning; bf16 table; fixed-point INT LDS accumulate.
// R16/R18: in-kernel deletions NEUTRAL => cost is structural.
// R19 PROBE: kernel trio = 43.6us, harness floor = 94.7us.
// R20 PROBE: global u64 atomics 147us => dead end. P~4.5us, F~1us.
// R21 PROBE: scatter (warm) = 18.4us/instance => S~18, B~20. BOTH far
//   above static models (S model ~8, B model ~4). Neither kernel's
//   rocprof counters have ever been visible (they sit below the 42us
//   harness fills in the top-5).
// R22 (this round): SINGLE-VARIABLE AMPLIFICATION PROBE on bucket.
//   Bucket runs its body 8x internally (re-zero acc -> accumulate ->
//   finalize, every rep; int fixed-point is order-invariant, finalize
//   rewrites identical bits => output bit-identical to R18).
//   Yields: (a) dur = 138.3 + 7*B_warm  => precise B + cold-vs-warm
//   split; (b) bucket dispatches ~8*B ~ 160us displace fills from
//   top-5 => FIRST real counters for bucket (VALUBusy, Occupancy,
//   FETCH, SQ_LDS_BANK_CONFLICT — suspect acc u64 layout hits only 8
//   of 32 banks: bank=(4*dl)%32 => ~8-way conflict per ds_atomic).
//   Pre-commit: dur~278 => issue/structure-bound; dur~175-210 =>
//   cold-latency-bound. Scatter/precompute untouched.

#define VB 256           // vertices per bucket
#define VB_SHIFT 8
#define MAXNB 400        // NB = ceil(V/256) = 391 for V=100000
#define CHUNK 3125       // edges per chunk
#define NCHUNK 512       // chunks (E/CHUNK)
#define BIGT 1024
#define CAP_SHIFT 13
#define CAP (1 << CAP_SHIFT)   // 8192 payload slots per bin
#define BREPS 8          // bucket internal replay factor (probe)
#define FIXS 131072.0f   // 2^17 fixed-point scale
#define FIXSI (1.0f / 131072.0f)
#define BIASI (1 << 22)  // low-field bias (|v_fix| < 2^22 since |v| < 32)

typedef unsigned int uint32;
typedef unsigned long long uint64;

static __device__ __forceinline__ uint32 f2bf(float f) {
    uint32 u = __float_as_uint(f);
    return (u + 0x7FFFu + ((u >> 16) & 1u)) >> 16;   // RNE to bf16
}
static __device__ __forceinline__ uint32 pack2(float lo, float hi) {
    return f2bf(lo) | (f2bf(hi) << 16);
}
static __device__ __forceinline__ float bf_lo(uint32 u) {
    return __uint_as_float(u << 16);
}
static __device__ __forceinline__ float bf_hi(uint32 u) {
    return __uint_as_float(u & 0xFFFF0000u);
}

// K1: per-vertex dot-product table (256 rows staged in LDS, stride 49
// floats, conflict-free). Block 0 zeroes the bin cursors.
__global__ __launch_bounds__(256)
void precompute_kernel(const float* __restrict__ x,
                       const float* __restrict__ w_self0,
                       const float* __restrict__ w_n00,
                       const float* __restrict__ w_n10,
                       const float* __restrict__ w_self11,
                       const float* __restrict__ w_n01,
                       const float* __restrict__ w_n11,
                       uint32* __restrict__ table,   // 8 u32/vertex
                       float* __restrict__ selfbuf,
                       int* __restrict__ fill,
                       int V, int NB) {
    __shared__ float stage[256 * 49];   // 50KB
    int tid = threadIdx.x;
    if (blockIdx.x == 0) {
        for (int i = tid; i < MAXNB; i += 256) fill[i] = 0;
    }
    int v0 = blockIdx.x * 256;
    int nv = min(256, V - v0);
    if (nv <= 0) return;
    {
        const float4* x4 = (const float4*)(x + (size_t)v0 * 48);
        int n4 = nv * 12;
        for (int j = tid; j < n4; j += 256) {
            float4 f = x4[j];
            float* dp = stage + (j / 12) * 49 + (j % 12) * 4;
            dp[0] = f.x; dp[1] = f.y; dp[2] = f.z; dp[3] = f.w;
        }
    }
    __syncthreads();
    if (tid >= nv) return;
    int v = v0 + tid;
    const float* xr = stage + tid * 49;
    float d00 = 0.f, aw0 = 0.f, bw0 = 0.f, aw1 = 0.f, bw1 = 0.f;
    float d01a = 0.f, d01b = 0.f;
    float aP = 0.f, bP = 0.f, aQ = 0.f, bQ = 0.f;
    float aR = 0.f, bR = 0.f, aS = 0.f, bS = 0.f;
    float selfmag = 0.f, t1s = 0.f, t2s = 0.f;
#pragma unroll
    for (int i = 0; i < 16; ++i) {
        float x0 = xr[i];
        float a  = xr[16 + 2 * i];
        float b  = xr[17 + 2 * i];
        d00     += x0 * w_n00[i];
        selfmag += x0 * w_self0[i];
        d01a    += x0 * w_n01[i * 2 + 0];
        d01b    += x0 * w_n01[i * 2 + 1];
        float w0 = w_n10[i * 2 + 0], w1 = w_n10[i * 2 + 1];
        aw0 += a * w0;  bw0 += b * w0;
        aw1 += a * w1;  bw1 += b * w1;
        float p = w_n11[i * 4 + 0], q = w_n11[i * 4 + 1];
        float r = w_n11[i * 4 + 2], s = w_n11[i * 4 + 3];
        aP += a * p;  bP += b * p;
        aQ += a * q;  bQ += b * q;
        aR += a * r;  bR += b * r;
        aS += a * s;  bS += b * s;
        float sa_ = w_self11[i * 2 + 0], sb_ = w_self11[i * 2 + 1];
        t1s += a * sa_ - b * sb_;
        t2s += b * sa_ + a * sb_;
    }
    uint4 w0, w1;
    w0.x = pack2(d00, aw0);  w0.y = pack2(bw0, aw1);
    w0.z = pack2(bw1, d01a); w0.w = pack2(d01b, aP);
    w1.x = pack2(bP, aQ);    w1.y = pack2(bQ, aR);
    w1.z = pack2(bR, aS);    w1.w = pack2(bS, 0.f);
    uint4* tp = (uint4*)(table + (size_t)v * 8);
    tp[0] = w0;  tp[1] = w1;
    float* sf = selfbuf + (size_t)v * 4;
    sf[0] = selfmag; sf[1] = t1s; sf[2] = t2s; sf[3] = 0.f;
}

// K2: per-chunk LDS tuple-sort + compute + write into the bin's global
// region reserved via one atomicAdd per (chunk,bin). (Unchanged R18.)
__global__ __launch_bounds__(BIGT)
void scatter_kernel(const int* __restrict__ src,
                    const int* __restrict__ dst,
                    const float* __restrict__ angles,
                    const float* __restrict__ transporters,
                    const uint32* __restrict__ table,
                    int* __restrict__ fill,
                    uint2* __restrict__ payload,
                    int E, int NB) {
    __shared__ int cnt_l[MAXNB];
    __shared__ int exoff_l[MAXNB];
    __shared__ int slot_l[MAXNB];
    __shared__ int wsum[16];
    __shared__ uint32 tw_src[CHUNK];
    __shared__ uint32 tw_ang[CHUNK];
    __shared__ uint32 tw_tr[CHUNK];
    __shared__ unsigned short tw_bin[CHUNK];

    int b = blockIdx.x;
    int lo = b * CHUNK;
    int hi = min(E, lo + CHUNK);
    int nloc = hi - lo;
    int tid = threadIdx.x;
    int lane = tid & 63;
    int wv = tid >> 6;

    for (int i = tid; i < NB; i += BIGT) cnt_l[i] = 0;
    __syncthreads();

    // pass1: chunk histogram (dst stays L1-warm for pass1b)
    for (int e = lo + tid; e < hi; e += BIGT)
        atomicAdd(&cnt_l[dst[e] >> VB_SHIFT], 1);
    __syncthreads();

    // reserve global bin space NOW (latency overlaps the scan below)
    int c = (tid < NB) ? cnt_l[tid] : 0;
    int rsv = 0;
    if (tid < NB && c > 0) rsv = atomicAdd(&fill[tid], c);

    // exclusive scan of chunk bin counts -> local sort offsets
    int incl = c;
#pragma unroll
    for (int d = 1; d < 64; d <<= 1) {
        int n = __shfl_up(incl, d);
        if (lane >= d) incl += n;
    }
    if (lane == 63) wsum[wv] = incl;
    __syncthreads();
    if (tid < 16) {
        int wval = wsum[tid], winc = wval;
#pragma unroll
        for (int d = 1; d < 16; d <<= 1) {
            int n = __shfl_up(winc, d);
            if (lane >= d) winc += n;
        }
        wsum[tid] = winc - wval;
    }
    __syncthreads();
    if (tid < NB) {
        int ex = incl - c + wsum[wv];
        exoff_l[tid] = ex;
        cnt_l[tid] = ex;                             // cursor
        slot_l[tid] = (tid << CAP_SHIFT) + rsv;      // global run start
    }
    __syncthreads();

    // pass1b: coalesced reads; tuple -> bin-sorted LDS slot
    for (int e = lo + tid; e < hi; e += BIGT) {
        int d = dst[e];
        int bin = d >> VB_SHIFT;
        uint32 dl = (uint32)(d & (VB - 1));
        int pos = atomicAdd(&cnt_l[bin], 1);
        tw_src[pos] = (uint32)src[e] | (dl << 17);
        tw_ang[pos] = __float_as_uint(angles[e]);
        tw_tr[pos]  = __float_as_uint(transporters[e]);
        tw_bin[pos] = (unsigned short)bin;
    }
    __syncthreads();

    // pass2: compute in bin order, write contiguous bin-region runs
    for (int k = tid; k < nloc; k += BIGT) {
        int bin = (int)tw_bin[k];
        uint32 w0i = tw_src[k];
        int s  = (int)(w0i & 0x1FFFFu);
        int dl = (int)(w0i >> 17);
        float ang = __uint_as_float(tw_ang[k]);
        float trv = __uint_as_float(tw_tr[k]);
        // native trig: args in [0, 2pi), err ~1e-6 << bf16 payload err
        float st = __sinf(ang), ct = __cosf(ang);
        float sg = __sinf(trv), cg = __cosf(trv);
        float c2t = ct * ct - st * st;
        float s2t = 2.0f * st * ct;

        const uint4* tp = (const uint4*)(table + (size_t)s * 8);
        uint4 W0 = tp[0], W1 = tp[1];
        float d00 = bf_lo(W0.x), aw0 = bf_hi(W0.x);
        float bw0 = bf_lo(W0.y), aw1 = bf_hi(W0.y);
        float bw1 = bf_lo(W0.z), d01a = bf_hi(W0.z);
        float d01b = bf_lo(W0.w), aP = bf_hi(W0.w);
        float bP = bf_lo(W1.x), aQ = bf_hi(W1.x);
        float bQ = bf_lo(W1.y), aR = bf_hi(W1.y);
        float bR = bf_lo(W1.z), aS = bf_hi(W1.z);
        float bS = bf_lo(W1.w);

        float u1w0 = cg * aw0 - sg * bw0, u2w0 = sg * aw0 + cg * bw0;
        float u1w1 = cg * aw1 - sg * bw1, u2w1 = sg * aw1 + cg * bw1;
        float m0 = d00 + ct * u1w0 + st * u2w0 - st * u1w1 + ct * u2w1;

        float u1p = cg * aP - sg * bP, u2p = sg * aP + cg * bP;
        float u1q = cg * aQ - sg * bQ, u2q = sg * aQ + cg * bQ;
        float u1r = cg * aR - sg * bR, u2r = sg * aR + cg * bR;
        float u1s = cg * aS - sg * bS, u2s = sg * aS + cg * bS;

        float mv1 = d01a * ct - d01b * st
                  + u1p - u2q
                  + c2t * u1r + s2t * u2r
                  - (s2t * u1s - c2t * u2s);
        float mv2 = d01a * st + d01b * ct
                  + u2p + u1q
                  + s2t * u1r - c2t * u2r
                  + c2t * u1s + s2t * u2s;

        uint2 pl;
        pl.x = pack2(m0, mv1);
        pl.y = f2bf(mv2) | ((uint32)dl << 16);
        int g = slot_l[bin] + (k - exoff_l[bin]);
        if (g < ((bin + 1) << CAP_SHIFT))            // overflow clamp
            payload[g] = pl;
    }
}

// K3 (PROBE: 8x internal replay): one block per bin. Each rep: zero acc,
// accumulate (2 packed u64 LDS atomics/edge), finalize (idempotent —
// identical bits every rep). dur delta measures warm per-rep cost;
// dispatch length ~8*B puts bucket in rocprof top-5 with counters.
__global__ __launch_bounds__(BIGT)
void bucket_kernel(const uint2* __restrict__ payload,
                   const int* __restrict__ fill,
                   const float* __restrict__ selfbuf,
                   const float* __restrict__ e1,
                   const float* __restrict__ e2,
                   float* __restrict__ out,
                   int V) {
    __shared__ uint64 acc[8][VB * 2];    // 32KB, wave-pair w=tid>>7 owns copy
    int bin = blockIdx.x;
    int tid = threadIdx.x;
    int n = min(fill[bin], CAP);
    const uint2* pp = payload + ((size_t)bin << CAP_SHIFT);
    uint64* myacc = acc[tid >> 7];

    for (int rep = 0; rep < BREPS; ++rep) {
        for (int i = tid; i < 8 * VB * 2; i += BIGT) ((uint64*)acc)[i] = 0ULL;
        __syncthreads();

        for (int k = tid; k < n; k += BIGT) {
            uint2 pl = pp[k];
            float m0  = bf_lo(pl.x);
            float mv1 = bf_hi(pl.x);
            float mv2 = bf_lo(pl.y);
            int dl = (int)(pl.y >> 16);
            int m0f  = __float2int_rn(m0  * FIXS);
            int mv1f = __float2int_rn(mv1 * FIXS);
            int mv2f = __float2int_rn(mv2 * FIXS);
            uint64 pa = (uint64)(uint32)(m0f + BIASI)
                      | ((uint64)(uint32)mv1f << 32);
            uint64 pb = (uint64)(uint32)(mv2f + BIASI)
                      | (1ULL << 32);
            atomicAdd(&myacc[dl * 2 + 0], pa);
            atomicAdd(&myacc[dl * 2 + 1], pb);
        }
        __syncthreads();

        if (tid < VB) {
            int v = bin * VB + tid;
            if (v < V) {
                int cnt = 0, m0s = 0, mv1s = 0, mv2s = 0;
#pragma unroll
                for (int w = 0; w < 8; ++w) {
                    uint64 a = acc[w][tid * 2 + 0];
                    uint64 b = acc[w][tid * 2 + 1];
                    uint32 nw = (uint32)(b >> 32);
                    cnt  += (int)nw;
                    m0s  += (int)((uint32)a - nw * (uint32)BIASI);
                    mv1s += (int)(a >> 32);
                    mv2s += (int)((uint32)b - nw * (uint32)BIASI);
                }
                float A0 = (float)m0s  * FIXSI;
                float A1 = (float)mv1s * FIXSI;
                float A2 = (float)mv2s * FIXSI;
                float inv = 1.0f / fmaxf((float)cnt, 1.0f);
                const float* sf = selfbuf + (size_t)v * 4;
                float mag = A0 * inv + sf[0];
                float t1  = A1 * inv + sf[1];
                float t2  = A2 * inv + sf[2];
                float scale = 2.0f / (1.0f + expf(-mag));
                float e1x = e1[v * 3 + 0], e1y = e1[v * 3 + 1], e1z = e1[v * 3 + 2];
                float e2x = e2[v * 3 + 0], e2y = e2[v * 3 + 1], e2z = e2[v * 3 + 2];
                out[v * 3 + 0] = (t1 * e1x + t2 * e2x) * scale;
                out[v * 3 + 1] = (t1 * e1y + t2 * e2y) * scale;
                out[v * 3 + 2] = (t1 * e1z + t2 * e2z) * scale;
            }
        }
        __syncthreads();   // protect acc from next rep's zeroing
    }
}

extern "C" void kernel_launch(void* const* d_in, const int* in_sizes, int n_in,
                              void* d_out, int out_size, void* d_ws, size_t ws_size,
                              hipStream_t stream) {
    const float* x            = (const float*)d_in[0];
    const int*   edge_index   = (const int*)d_in[1];
    const float* angles       = (const float*)d_in[2];
    const float* transporters = (const float*)d_in[3];
    const float* e1           = (const float*)d_in[4];
    const float* e2           = (const float*)d_in[5];
    const float* w_self0      = (const float*)d_in[6];
    const float* w_n00        = (const float*)d_in[7];
    const float* w_n10        = (const float*)d_in[8];
    const float* w_self11     = (const float*)d_in[9];
    const float* w_n01        = (const float*)d_in[10];
    const float* w_n11        = (const float*)d_in[11];
    float* out = (float*)d_out;

    int V = in_sizes[0] / 48;
    int E = in_sizes[2];
    const int* src = edge_index;
    const int* dst = edge_index + E;

    int NB = (V + VB - 1) / VB;              // 391
    int nchunk = (E + CHUNK - 1) / CHUNK;    // 512

    char* p = (char*)d_ws;
    int* fill      = (int*)p;     p += (size_t)MAXNB * 4;
    uint32* table  = (uint32*)p;  p += (size_t)V * 8 * 4;         // 3.2MB
    float* selfbuf = (float*)p;   p += (size_t)V * 4 * 4;         // 1.6MB
    p = (char*)(((uintptr_t)p + 63) & ~(uintptr_t)63);
    uint2* payload = (uint2*)p;   // MAXNB * CAP * 8B = 26.2MB

    int gv = (V + 255) / 256;                // 391

    precompute_kernel<<<gv, 256, 0, stream>>>(
        x, w_self0, w_n00, w_n10, w_self11, w_n01, w_n11,
        table, selfbuf, fill, V, NB);
    scatter_kernel<<<nchunk, BIGT, 0, stream>>>(src, dst, angles,
                                                transporters, table,
                                                fill, payload, E, NB);
    bucket_kernel<<<NB, BIGT, 0, stream>>>(payload, fill, selfbuf,
                                           e1, e2, out, V);
}

// Round 8
// 146.280 us; speedup vs baseline: 1.8280x; 1.1265x over previous
//
#include <hip/hip_runtime.h>
#include <math.h>

// EquivariantWSSHead: V=100000 vertices, E=1600000 edges, C0=C1=16.
//
// R1..R15: bucket binning; bf16 table; fixed-point INT LDS accumulate.
// R16/R18: in-kernel deletions NEUTRAL => cost is structural.
// R19 PROBE: kernel trio = 43.6us, harness floor = 94.7us.
// R20 PROBE: global u64 atomics 147us => dead end. P~4, F~1.
// R21 PROBE: scatter (warm, +gap) = 18.4us.
// R22 PROBE: bucket warm BODY = 3.79us/rep => bucket's ~16us pipeline
//   cost is ~12us COLD/first-touch, not compute. Ledger: floor 94.7 |
//   P 3-4 | S 17-18 | B 14-17 (body 4) | F 1.
// R23 (this round): both anomalies share one root cause — R18 dropped
//   the payload line alignment R14 had measured as critical. Runs land
//   at arbitrary 8B offsets => ~200K partial-line writes (RMW at L2/HBM)
//   in scatter, then bucket cold-reads those dirty straddling lines
//   back across XCDs. Fix: PADDED cursor reservation — reserve
//   cpad=(c+7)&~7 slots per (chunk,bin) (64B-aligned full-line runs),
//   fill pads with sentinel entries {0,0xFFFF0000} (real high word
//   <=255), bucket skips sentinels with one compare. Padded totals
//   ~6K < CAP 8192; clamps retained. Falsifier: dur>=136 => RMW theory
//   dead; next round = scatter x4 INTERNAL replay for counters.

#define VB 256           // vertices per bucket
#define VB_SHIFT 8
#define MAXNB 400        // NB = ceil(V/256) = 391 for V=100000
#define CHUNK 3125       // edges per chunk
#define NCHUNK 512       // chunks (E/CHUNK)
#define BIGT 1024
#define CAP_SHIFT 13
#define CAP (1 << CAP_SHIFT)   // 8192 payload slots per bin
#define FIXS 131072.0f   // 2^17 fixed-point scale
#define FIXSI (1.0f / 131072.0f)
#define BIASI (1 << 22)  // low-field bias (|v_fix| < 2^22 since |v| < 32)

typedef unsigned int uint32;
typedef unsigned long long uint64;

static __device__ __forceinline__ uint32 f2bf(float f) {
    uint32 u = __float_as_uint(f);
    return (u + 0x7FFFu + ((u >> 16) & 1u)) >> 16;   // RNE to bf16
}
static __device__ __forceinline__ uint32 pack2(float lo, float hi) {
    return f2bf(lo) | (f2bf(hi) << 16);
}
static __device__ __forceinline__ float bf_lo(uint32 u) {
    return __uint_as_float(u << 16);
}
static __device__ __forceinline__ float bf_hi(uint32 u) {
    return __uint_as_float(u & 0xFFFF0000u);
}

// K1: per-vertex dot-product table (256 rows staged in LDS, stride 49
// floats, conflict-free). Block 0 zeroes the bin cursors.
__global__ __launch_bounds__(256)
void precompute_kernel(const float* __restrict__ x,
                       const float* __restrict__ w_self0,
                       const float* __restrict__ w_n00,
                       const float* __restrict__ w_n10,
                       const float* __restrict__ w_self11,
                       const float* __restrict__ w_n01,
                       const float* __restrict__ w_n11,
                       uint32* __restrict__ table,   // 8 u32/vertex
                       float* __restrict__ selfbuf,
                       int* __restrict__ fill,
                       int V, int NB) {
    __shared__ float stage[256 * 49];   // 50KB
    int tid = threadIdx.x;
    if (blockIdx.x == 0) {
        for (int i = tid; i < MAXNB; i += 256) fill[i] = 0;
    }
    int v0 = blockIdx.x * 256;
    int nv = min(256, V - v0);
    if (nv <= 0) return;
    {
        const float4* x4 = (const float4*)(x + (size_t)v0 * 48);
        int n4 = nv * 12;
        for (int j = tid; j < n4; j += 256) {
            float4 f = x4[j];
            float* dp = stage + (j / 12) * 49 + (j % 12) * 4;
            dp[0] = f.x; dp[1] = f.y; dp[2] = f.z; dp[3] = f.w;
        }
    }
    __syncthreads();
    if (tid >= nv) return;
    int v = v0 + tid;
    const float* xr = stage + tid * 49;
    float d00 = 0.f, aw0 = 0.f, bw0 = 0.f, aw1 = 0.f, bw1 = 0.f;
    float d01a = 0.f, d01b = 0.f;
    float aP = 0.f, bP = 0.f, aQ = 0.f, bQ = 0.f;
    float aR = 0.f, bR = 0.f, aS = 0.f, bS = 0.f;
    float selfmag = 0.f, t1s = 0.f, t2s = 0.f;
#pragma unroll
    for (int i = 0; i < 16; ++i) {
        float x0 = xr[i];
        float a  = xr[16 + 2 * i];
        float b  = xr[17 + 2 * i];
        d00     += x0 * w_n00[i];
        selfmag += x0 * w_self0[i];
        d01a    += x0 * w_n01[i * 2 + 0];
        d01b    += x0 * w_n01[i * 2 + 1];
        float w0 = w_n10[i * 2 + 0], w1 = w_n10[i * 2 + 1];
        aw0 += a * w0;  bw0 += b * w0;
        aw1 += a * w1;  bw1 += b * w1;
        float p = w_n11[i * 4 + 0], q = w_n11[i * 4 + 1];
        float r = w_n11[i * 4 + 2], s = w_n11[i * 4 + 3];
        aP += a * p;  bP += b * p;
        aQ += a * q;  bQ += b * q;
        aR += a * r;  bR += b * r;
        aS += a * s;  bS += b * s;
        float sa_ = w_self11[i * 2 + 0], sb_ = w_self11[i * 2 + 1];
        t1s += a * sa_ - b * sb_;
        t2s += b * sa_ + a * sb_;
    }
    uint4 w0, w1;
    w0.x = pack2(d00, aw0);  w0.y = pack2(bw0, aw1);
    w0.z = pack2(bw1, d01a); w0.w = pack2(d01b, aP);
    w1.x = pack2(bP, aQ);    w1.y = pack2(bQ, aR);
    w1.z = pack2(bR, aS);    w1.w = pack2(bS, 0.f);
    uint4* tp = (uint4*)(table + (size_t)v * 8);
    tp[0] = w0;  tp[1] = w1;
    float* sf = selfbuf + (size_t)v * 4;
    sf[0] = selfmag; sf[1] = t1s; sf[2] = t2s; sf[3] = 0.f;
}

// K2: per-chunk LDS tuple-sort + compute + write into the bin's global
// region. PADDED reservation: cpad=(c+7)&~7 slots => every run starts
// 64B-aligned and covers full lines; pad slots get sentinel entries
// (high word 0xFFFF; real entries have high word <= 255).
__global__ __launch_bounds__(BIGT)
void scatter_kernel(const int* __restrict__ src,
                    const int* __restrict__ dst,
                    const float* __restrict__ angles,
                    const float* __restrict__ transporters,
                    const uint32* __restrict__ table,
                    int* __restrict__ fill,
                    uint2* __restrict__ payload,
                    int E, int NB) {
    __shared__ int cnt_l[MAXNB];
    __shared__ int exoff_l[MAXNB];
    __shared__ int slot_l[MAXNB];
    __shared__ int wsum[16];
    __shared__ uint32 tw_src[CHUNK];
    __shared__ uint32 tw_ang[CHUNK];
    __shared__ uint32 tw_tr[CHUNK];
    __shared__ unsigned short tw_bin[CHUNK];

    int b = blockIdx.x;
    int lo = b * CHUNK;
    int hi = min(E, lo + CHUNK);
    int nloc = hi - lo;
    int tid = threadIdx.x;
    int lane = tid & 63;
    int wv = tid >> 6;

    for (int i = tid; i < NB; i += BIGT) cnt_l[i] = 0;
    __syncthreads();

    // pass1: chunk histogram (dst stays L1-warm for pass1b)
    for (int e = lo + tid; e < hi; e += BIGT)
        atomicAdd(&cnt_l[dst[e] >> VB_SHIFT], 1);
    __syncthreads();

    // padded reservation (latency overlaps the scan below)
    int c = (tid < NB) ? cnt_l[tid] : 0;
    int cpad = (c + 7) & ~7;                 // 64B-aligned run length
    int rsv = 0;
    if (tid < NB && c > 0) rsv = atomicAdd(&fill[tid], cpad);

    // exclusive scan of chunk bin counts -> local sort offsets
    int incl = c;
#pragma unroll
    for (int d = 1; d < 64; d <<= 1) {
        int n = __shfl_up(incl, d);
        if (lane >= d) incl += n;
    }
    if (lane == 63) wsum[wv] = incl;
    __syncthreads();
    if (tid < 16) {
        int wval = wsum[tid], winc = wval;
#pragma unroll
        for (int d = 1; d < 16; d <<= 1) {
            int n = __shfl_up(winc, d);
            if (lane >= d) winc += n;
        }
        wsum[tid] = winc - wval;
    }
    __syncthreads();
    int myslot = (tid << CAP_SHIFT) + rsv;   // 64B-aligned run start
    if (tid < NB) {
        int ex = incl - c + wsum[wv];
        exoff_l[tid] = ex;
        cnt_l[tid] = ex;                     // cursor
        slot_l[tid] = myslot;
    }
    __syncthreads();

    // sentinel-fill the pad tail of this chunk's run in each bin
    // (lines are completed here; pass2 fills the head; L2 merges)
    if (tid < NB && c > 0) {
        uint2 sent; sent.x = 0u; sent.y = 0xFFFF0000u;
        int lim = (tid + 1) << CAP_SHIFT;
        for (int j = c; j < cpad; ++j) {
            int g = myslot + j;
            if (g < lim) payload[g] = sent;  // overflow clamp
        }
    }

    // pass1b: coalesced reads; tuple -> bin-sorted LDS slot
    for (int e = lo + tid; e < hi; e += BIGT) {
        int d = dst[e];
        int bin = d >> VB_SHIFT;
        uint32 dl = (uint32)(d & (VB - 1));
        int pos = atomicAdd(&cnt_l[bin], 1);
        tw_src[pos] = (uint32)src[e] | (dl << 17);
        tw_ang[pos] = __float_as_uint(angles[e]);
        tw_tr[pos]  = __float_as_uint(transporters[e]);
        tw_bin[pos] = (unsigned short)bin;
    }
    __syncthreads();

    // pass2: compute in bin order, write line-aligned bin-region runs
    for (int k = tid; k < nloc; k += BIGT) {
        int bin = (int)tw_bin[k];
        uint32 w0i = tw_src[k];
        int s  = (int)(w0i & 0x1FFFFu);
        int dl = (int)(w0i >> 17);
        float ang = __uint_as_float(tw_ang[k]);
        float trv = __uint_as_float(tw_tr[k]);
        // native trig: args in [0, 2pi), err ~1e-6 << bf16 payload err
        float st = __sinf(ang), ct = __cosf(ang);
        float sg = __sinf(trv), cg = __cosf(trv);
        float c2t = ct * ct - st * st;
        float s2t = 2.0f * st * ct;

        const uint4* tp = (const uint4*)(table + (size_t)s * 8);
        uint4 W0 = tp[0], W1 = tp[1];
        float d00 = bf_lo(W0.x), aw0 = bf_hi(W0.x);
        float bw0 = bf_lo(W0.y), aw1 = bf_hi(W0.y);
        float bw1 = bf_lo(W0.z), d01a = bf_hi(W0.z);
        float d01b = bf_lo(W0.w), aP = bf_hi(W0.w);
        float bP = bf_lo(W1.x), aQ = bf_hi(W1.x);
        float bQ = bf_lo(W1.y), aR = bf_hi(W1.y);
        float bR = bf_lo(W1.z), aS = bf_hi(W1.z);
        float bS = bf_lo(W1.w);

        float u1w0 = cg * aw0 - sg * bw0, u2w0 = sg * aw0 + cg * bw0;
        float u1w1 = cg * aw1 - sg * bw1, u2w1 = sg * aw1 + cg * bw1;
        float m0 = d00 + ct * u1w0 + st * u2w0 - st * u1w1 + ct * u2w1;

        float u1p = cg * aP - sg * bP, u2p = sg * aP + cg * bP;
        float u1q = cg * aQ - sg * bQ, u2q = sg * aQ + cg * bQ;
        float u1r = cg * aR - sg * bR, u2r = sg * aR + cg * bR;
        float u1s = cg * aS - sg * bS, u2s = sg * aS + cg * bS;

        float mv1 = d01a * ct - d01b * st
                  + u1p - u2q
                  + c2t * u1r + s2t * u2r
                  - (s2t * u1s - c2t * u2s);
        float mv2 = d01a * st + d01b * ct
                  + u2p + u1q
                  + s2t * u1r - c2t * u2r
                  + c2t * u1s + s2t * u2s;

        uint2 pl;
        pl.x = pack2(m0, mv1);
        pl.y = f2bf(mv2) | ((uint32)dl << 16);
        int g = slot_l[bin] + (k - exoff_l[bin]);
        if (g < ((bin + 1) << CAP_SHIFT))            // overflow clamp
            payload[g] = pl;
    }
}

// K3: one block per bin. Dense aligned-line stream of the bin's padded
// region; sentinel entries (high word >= VB) skipped with one compare;
// TWO packed u64 fixed-point LDS atomics per real edge; fused finalize.
__global__ __launch_bounds__(BIGT)
void bucket_kernel(const uint2* __restrict__ payload,
                   const int* __restrict__ fill,
                   const float* __restrict__ selfbuf,
                   const float* __restrict__ e1,
                   const float* __restrict__ e2,
                   float* __restrict__ out,
                   int V) {
    __shared__ uint64 acc[8][VB * 2];    // 32KB, wave-pair w=tid>>7 owns copy
    int bin = blockIdx.x;
    int tid = threadIdx.x;
    for (int i = tid; i < 8 * VB * 2; i += BIGT) ((uint64*)acc)[i] = 0ULL;
    __syncthreads();

    int n = min(fill[bin], CAP);
    const uint2* pp = payload + ((size_t)bin << CAP_SHIFT);
    uint64* myacc = acc[tid >> 7];
    for (int k = tid; k < n; k += BIGT) {
        uint2 pl = pp[k];
        int dl = (int)(pl.y >> 16);
        if (dl < VB) {                       // sentinel pads skipped
            float m0  = bf_lo(pl.x);
            float mv1 = bf_hi(pl.x);
            float mv2 = bf_lo(pl.y);
            int m0f  = __float2int_rn(m0  * FIXS);
            int mv1f = __float2int_rn(mv1 * FIXS);
            int mv2f = __float2int_rn(mv2 * FIXS);
            uint64 pa = (uint64)(uint32)(m0f + BIASI)
                      | ((uint64)(uint32)mv1f << 32);
            uint64 pb = (uint64)(uint32)(mv2f + BIASI)
                      | (1ULL << 32);
            atomicAdd(&myacc[dl * 2 + 0], pa);
            atomicAdd(&myacc[dl * 2 + 1], pb);
        }
    }
    __syncthreads();
    if (tid < VB) {
        int v = bin * VB + tid;
        if (v < V) {
            int cnt = 0, m0s = 0, mv1s = 0, mv2s = 0;
#pragma unroll
            for (int w = 0; w < 8; ++w) {
                uint64 a = acc[w][tid * 2 + 0];
                uint64 b = acc[w][tid * 2 + 1];
                uint32 nw = (uint32)(b >> 32);
                cnt  += (int)nw;
                m0s  += (int)((uint32)a - nw * (uint32)BIASI);
                mv1s += (int)(a >> 32);
                mv2s += (int)((uint32)b - nw * (uint32)BIASI);
            }
            float A0 = (float)m0s  * FIXSI;
            float A1 = (float)mv1s * FIXSI;
            float A2 = (float)mv2s * FIXSI;
            float inv = 1.0f / fmaxf((float)cnt, 1.0f);
            const float* sf = selfbuf + (size_t)v * 4;
            float mag = A0 * inv + sf[0];
            float t1  = A1 * inv + sf[1];
            float t2  = A2 * inv + sf[2];
            float scale = 2.0f / (1.0f + expf(-mag));
            float e1x = e1[v * 3 + 0], e1y = e1[v * 3 + 1], e1z = e1[v * 3 + 2];
            float e2x = e2[v * 3 + 0], e2y = e2[v * 3 + 1], e2z = e2[v * 3 + 2];
            out[v * 3 + 0] = (t1 * e1x + t2 * e2x) * scale;
            out[v * 3 + 1] = (t1 * e1y + t2 * e2y) * scale;
            out[v * 3 + 2] = (t1 * e1z + t2 * e2z) * scale;
        }
    }
}

extern "C" void kernel_launch(void* const* d_in, const int* in_sizes, int n_in,
                              void* d_out, int out_size, void* d_ws, size_t ws_size,
                              hipStream_t stream) {
    const float* x            = (const float*)d_in[0];
    const int*   edge_index   = (const int*)d_in[1];
    const float* angles       = (const float*)d_in[2];
    const float* transporters = (const float*)d_in[3];
    const float* e1           = (const float*)d_in[4];
    const float* e2           = (const float*)d_in[5];
    const float* w_self0      = (const float*)d_in[6];
    const float* w_n00        = (const float*)d_in[7];
    const float* w_n10        = (const float*)d_in[8];
    const float* w_self11     = (const float*)d_in[9];
    const float* w_n01        = (const float*)d_in[10];
    const float* w_n11        = (const float*)d_in[11];
    float* out = (float*)d_out;

    int V = in_sizes[0] / 48;
    int E = in_sizes[2];
    const int* src = edge_index;
    const int* dst = edge_index + E;

    int NB = (V + VB - 1) / VB;              // 391
    int nchunk = (E + CHUNK - 1) / CHUNK;    // 512

    char* p = (char*)d_ws;
    int* fill      = (int*)p;     p += (size_t)MAXNB * 4;
    uint32* table  = (uint32*)p;  p += (size_t)V * 8 * 4;         // 3.2MB
    float* selfbuf = (float*)p;   p += (size_t)V * 4 * 4;         // 1.6MB
    p = (char*)(((uintptr_t)p + 63) & ~(uintptr_t)63);
    uint2* payload = (uint2*)p;   // MAXNB * CAP * 8B = 26.2MB

    int gv = (V + 255) / 256;                // 391

    precompute_kernel<<<gv, 256, 0, stream>>>(
        x, w_self0, w_n00, w_n10, w_self11, w_n01, w_n11,
        table, selfbuf, fill, V, NB);
    scatter_kernel<<<nchunk, BIGT, 0, stream>>>(src, dst, angles,
                                                transporters, table,
                                                fill, payload, E, NB);
    bucket_kernel<<<NB, BIGT, 0, stream>>>(payload, fill, selfbuf,
                                           e1, e2, out, V);
}